// Round 2
// baseline (479.001 us; speedup 1.0000x reference)
//
#include <hip/hip_runtime.h>

#define N_NODES 50000
#define N_EDGES 800000
#define D 128
#define GEMM_ROWS 16

// ---------------- degree histogram ----------------
__global__ void hist_kernel(const int* __restrict__ dst, int* __restrict__ cnt) {
    int e = blockIdx.x * blockDim.x + threadIdx.x;
    if (e < N_EDGES) {
        atomicAdd(&cnt[dst[e]], 1);
    }
}

// ---------------- exclusive scan: 1 block, thread-serial chunks + shfl block-scan ----
// 1024 threads x 49 contiguous elements = 50176 >= 50001.
#define SCAN_CHUNK 49
__global__ __launch_bounds__(1024) void scan_kernel(const int* __restrict__ cnt,
                                                    int* __restrict__ rowstart,
                                                    float* __restrict__ dis) {
    int t = threadIdx.x;
    int base = t * SCAN_CHUNK;
    // pass 1: local sum
    int sum = 0;
    #pragma unroll 7
    for (int i = 0; i < SCAN_CHUNK; i++) {
        int idx = base + i;
        if (idx < N_NODES) sum += cnt[idx];
    }
    // block exclusive scan of per-thread sums
    int lane = t & 63, wv = t >> 6;                // 16 waves
    int incl = sum;
    #pragma unroll
    for (int off = 1; off < 64; off <<= 1) {
        int u = __shfl_up(incl, off, 64);
        if (lane >= off) incl += u;
    }
    __shared__ int wsums[16];
    if (lane == 63) wsums[wv] = incl;
    __syncthreads();
    if (t < 16) {
        int v = wsums[t];
        #pragma unroll
        for (int off = 1; off < 16; off <<= 1) {
            int u = __shfl_up(v, off, 64);
            if (t >= off) v += u;
        }
        wsums[t] = v;                              // inclusive wave prefix
    }
    __syncthreads();
    int running = (wv > 0 ? wsums[wv - 1] : 0) + (incl - sum);  // thread-exclusive prefix
    // pass 2: write prefixes + dis (cnt re-read is L2-hot)
    #pragma unroll 7
    for (int i = 0; i < SCAN_CHUNK; i++) {
        int idx = base + i;
        if (idx <= N_NODES) {
            rowstart[idx] = running;
            if (idx < N_NODES) {
                int v = cnt[idx];
                running += v;
                dis[idx] = rsqrtf((float)(v + 1));   // +1 self-loop
            }
        }
    }
}

// ---------------- scatter edges into CSR ----------------
__global__ void scatter_kernel(const int* __restrict__ src, const int* __restrict__ dst,
                               const int* __restrict__ rowstart, int* __restrict__ cursor,
                               const float* __restrict__ dis,
                               int* __restrict__ col, float* __restrict__ wsrc) {
    int e = blockIdx.x * blockDim.x + threadIdx.x;
    if (e < N_EDGES) {
        int s = src[e], d = dst[e];
        int p = rowstart[d] + atomicAdd(&cursor[d], 1);
        col[p] = s;
        wsrc[p] = dis[s];
    }
}

// ---------------- H = X @ W  (fp32, vector ALU; no fp32 MFMA on CDNA4) ----------------
__global__ __launch_bounds__(256) void gemm_kernel(const float* __restrict__ X,
                                                   const float* __restrict__ W,
                                                   float* __restrict__ H) {
    __shared__ __align__(16) float Xs[GEMM_ROWS * D];
    int t = threadIdx.x;
    int rbase = blockIdx.x * GEMM_ROWS;
    for (int idx = t; idx < GEMM_ROWS * D; idx += 256)
        Xs[idx] = X[(size_t)rbase * D + idx];
    __syncthreads();
    int c  = t & 127;   // output column
    int rg = t >> 7;    // 0..1, 8 rows each
    float acc[8] = {0.f, 0.f, 0.f, 0.f, 0.f, 0.f, 0.f, 0.f};
    const float* Wc = W + c;            // W[k][c], row-major
    const float* Xr = Xs + (rg * 8) * D;
    #pragma unroll 2
    for (int k = 0; k < D; k += 4) {    // ds_read_b128 for X, 4 k-steps per chunk
        float w0 = Wc[(k + 0) * D];
        float w1 = Wc[(k + 1) * D];
        float w2 = Wc[(k + 2) * D];
        float w3 = Wc[(k + 3) * D];
        #pragma unroll
        for (int i = 0; i < 8; i++) {
            float4 xv = *(const float4*)&Xr[i * D + k];
            acc[i] = fmaf(xv.x, w0, acc[i]);
            acc[i] = fmaf(xv.y, w1, acc[i]);
            acc[i] = fmaf(xv.z, w2, acc[i]);
            acc[i] = fmaf(xv.w, w3, acc[i]);
        }
    }
    #pragma unroll
    for (int i = 0; i < 8; i++)
        H[(size_t)(rbase + rg * 8 + i) * D + c] = acc[i];
}

// ---------------- per-dst gather-aggregate + bias + ReLU (1 wave per node) --------
__global__ __launch_bounds__(256) void aggr_kernel(const float* __restrict__ Hin,
                                                   const float* __restrict__ dis,
                                                   const int* __restrict__ rowstart,
                                                   const int* __restrict__ col,
                                                   const float* __restrict__ wsrc,
                                                   const float* __restrict__ bias,
                                                   float* __restrict__ Hout) {
    int n = blockIdx.x * 4 + (threadIdx.x >> 6);
    if (n >= N_NODES) return;
    int t = threadIdx.x & 63;            // 2 channels per lane
    const float2* H2 = (const float2*)Hin;
    float disd = dis[n];
    float2 self = H2[(size_t)n * 64 + t];
    float w0 = disd * disd;              // self-loop weight
    float ax = self.x * w0, ay = self.y * w0;
    int beg = rowstart[n], end = rowstart[n + 1];
    int p = beg;
    for (; p + 1 < end; p += 2) {        // 2 independent gathers in flight
        int s0 = col[p], s1 = col[p + 1];
        float wA = wsrc[p] * disd, wB = wsrc[p + 1] * disd;
        float2 h0 = H2[(size_t)s0 * 64 + t];
        float2 h1 = H2[(size_t)s1 * 64 + t];
        ax += h0.x * wA + h1.x * wB;
        ay += h0.y * wA + h1.y * wB;
    }
    if (p < end) {
        int s = col[p];
        float w = wsrc[p] * disd;
        float2 hv = H2[(size_t)s * 64 + t];
        ax += hv.x * w;
        ay += hv.y * w;
    }
    float2 bb = ((const float2*)bias)[t];
    float2 o;
    o.x = fmaxf(ax + bb.x, 0.f);
    o.y = fmaxf(ay + bb.y, 0.f);
    ((float2*)Hout)[(size_t)n * 64 + t] = o;
}

extern "C" void kernel_launch(void* const* d_in, const int* in_sizes, int n_in,
                              void* d_out, int out_size, void* d_ws, size_t ws_size,
                              hipStream_t stream) {
    const float* x  = (const float*)d_in[0];
    const int*   ei = (const int*)d_in[1];   // int32 per harness contract
    const float* W1 = (const float*)d_in[2];
    const float* b1 = (const float*)d_in[3];
    const float* W2 = (const float*)d_in[4];
    const float* b2 = (const float*)d_in[5];
    float* out = (float*)d_out;

    char* ws = (char*)d_ws;
    size_t off = 0;
    auto alloc = [&](size_t bytes) -> void* {
        void* p = ws + off;
        off += (bytes + 255) & ~(size_t)255;
        return p;
    };
    int*   cnt      = (int*)alloc((size_t)N_NODES * 4);
    int*   cursor   = (int*)alloc((size_t)N_NODES * 4);
    int*   rowstart = (int*)alloc((size_t)(N_NODES + 1) * 4);
    float* dis      = (float*)alloc((size_t)N_NODES * 4);
    int*   col      = (int*)alloc((size_t)N_EDGES * 4);
    float* wsrc     = (float*)alloc((size_t)N_EDGES * 4);
    float* HA       = (float*)alloc((size_t)N_NODES * D * 4);
    float* HB       = (float*)alloc((size_t)N_NODES * D * 4);

    const int* src = ei;             // edge_index[0]
    const int* dst = ei + N_EDGES;   // edge_index[1]

    hipMemsetAsync(cnt, 0, (size_t)((char*)rowstart - (char*)cnt), stream);

    hist_kernel<<<(N_EDGES + 255) / 256, 256, 0, stream>>>(dst, cnt);
    scan_kernel<<<1, 1024, 0, stream>>>(cnt, rowstart, dis);
    scatter_kernel<<<(N_EDGES + 255) / 256, 256, 0, stream>>>(src, dst, rowstart, cursor,
                                                              dis, col, wsrc);

    gemm_kernel<<<N_NODES / GEMM_ROWS, 256, 0, stream>>>(x, W1, HA);
    aggr_kernel<<<(N_NODES + 3) / 4, 256, 0, stream>>>(HA, dis, rowstart, col, wsrc, b1, HB);
    gemm_kernel<<<N_NODES / GEMM_ROWS, 256, 0, stream>>>(HB, W2, HA);
    aggr_kernel<<<(N_NODES + 3) / 4, 256, 0, stream>>>(HA, dis, rowstart, col, wsrc, b2, out);
}

// Round 3
// 389.766 us; speedup vs baseline: 1.2289x; 1.2289x over previous
//
#include <hip/hip_runtime.h>

#define N_NODES 50000
#define N_EDGES 800000
#define D 128
#define GEMM_ROWS 16
#define SBLK 256
#define NSBLK ((N_NODES + SBLK - 1) / SBLK)   // 196

// ---------------- degree histogram ----------------
__global__ void hist_kernel(const int* __restrict__ dst, int* __restrict__ cnt) {
    int e = blockIdx.x * blockDim.x + threadIdx.x;
    if (e < N_EDGES) {
        atomicAdd(&cnt[dst[e]], 1);
    }
}

// ---------------- hierarchical scan, phase 1: block-local exclusive + block sums ----
__device__ __forceinline__ int block_incl_scan(int v, int t) {
    int lane = t & 63, wv = t >> 6;
    int incl = v;
    #pragma unroll
    for (int off = 1; off < 64; off <<= 1) {
        int u = __shfl_up(incl, off, 64);
        if (lane >= off) incl += u;
    }
    __shared__ int wsums[4];
    if (lane == 63) wsums[wv] = incl;
    __syncthreads();
    int add = 0;
    if (wv > 0) add += wsums[0];
    if (wv > 1) add += wsums[1];
    if (wv > 2) add += wsums[2];
    return incl + add;
}

__global__ __launch_bounds__(SBLK) void scan1_kernel(const int* __restrict__ cnt,
                                                     int* __restrict__ rowstart,
                                                     int* __restrict__ bsum) {
    int t = threadIdx.x, b = blockIdx.x;
    int i = b * SBLK + t;
    int v = (i < N_NODES) ? cnt[i] : 0;
    int incl = block_incl_scan(v, t);
    if (i < N_NODES) rowstart[i] = incl - v;       // block-local exclusive
    if (t == SBLK - 1) bsum[b] = incl;             // block total
}

// phase 2: scan the 196 block sums (one block), write total to rowstart[N]
__global__ __launch_bounds__(SBLK) void scan2_kernel(const int* __restrict__ bsum,
                                                     int* __restrict__ boff,
                                                     int* __restrict__ rowstart) {
    int t = threadIdx.x;
    int v = (t < NSBLK) ? bsum[t] : 0;
    int incl = block_incl_scan(v, t);
    if (t < NSBLK) boff[t] = incl - v;             // exclusive block offset
    if (t == SBLK - 1) rowstart[N_NODES] = incl;   // grand total = E
}

// phase 3: add block offsets; fused dis = rsqrt(deg+1)
__global__ __launch_bounds__(SBLK) void scan3_kernel(const int* __restrict__ cnt,
                                                     const int* __restrict__ boff,
                                                     int* __restrict__ rowstart,
                                                     float* __restrict__ dis) {
    int i = blockIdx.x * SBLK + threadIdx.x;
    if (i < N_NODES) {
        rowstart[i] += boff[blockIdx.x];
        dis[i] = rsqrtf((float)(cnt[i] + 1));      // +1 self-loop
    }
}

// ---------------- scatter edges into CSR (packed 8B record) ----------------
__global__ void scatter_kernel(const int* __restrict__ src, const int* __restrict__ dst,
                               const int* __restrict__ rowstart, int* __restrict__ cursor,
                               const float* __restrict__ dis,
                               int2* __restrict__ edge) {
    int e = blockIdx.x * blockDim.x + threadIdx.x;
    if (e < N_EDGES) {
        int s = src[e], d = dst[e];
        int p = rowstart[d] + atomicAdd(&cursor[d], 1);
        edge[p] = make_int2(s, __float_as_int(dis[s]));   // one scattered line, not two
    }
}

// ---------------- H = X @ W  (fp32, vector ALU; no fp32 MFMA on CDNA4) ----------------
__global__ __launch_bounds__(256) void gemm_kernel(const float* __restrict__ X,
                                                   const float* __restrict__ W,
                                                   float* __restrict__ H) {
    __shared__ __align__(16) float Xs[GEMM_ROWS * D];
    int t = threadIdx.x;
    int rbase = blockIdx.x * GEMM_ROWS;
    for (int idx = t; idx < GEMM_ROWS * D; idx += 256)
        Xs[idx] = X[(size_t)rbase * D + idx];
    __syncthreads();
    int c  = t & 127;   // output column
    int rg = t >> 7;    // 0..1, 8 rows each
    float acc[8] = {0.f, 0.f, 0.f, 0.f, 0.f, 0.f, 0.f, 0.f};
    const float* Wc = W + c;            // W[k][c], row-major
    const float* Xr = Xs + (rg * 8) * D;
    #pragma unroll 2
    for (int k = 0; k < D; k += 4) {    // ds_read_b128 for X
        float w0 = Wc[(k + 0) * D];
        float w1 = Wc[(k + 1) * D];
        float w2 = Wc[(k + 2) * D];
        float w3 = Wc[(k + 3) * D];
        #pragma unroll
        for (int i = 0; i < 8; i++) {
            float4 xv = *(const float4*)&Xr[i * D + k];
            acc[i] = fmaf(xv.x, w0, acc[i]);
            acc[i] = fmaf(xv.y, w1, acc[i]);
            acc[i] = fmaf(xv.z, w2, acc[i]);
            acc[i] = fmaf(xv.w, w3, acc[i]);
        }
    }
    #pragma unroll
    for (int i = 0; i < 8; i++)
        H[(size_t)(rbase + rg * 8 + i) * D + c] = acc[i];
}

// ---------------- per-dst gather-aggregate + bias + ReLU (1 wave per node) --------
__global__ __launch_bounds__(256) void aggr_kernel(const float* __restrict__ Hin,
                                                   const float* __restrict__ dis,
                                                   const int* __restrict__ rowstart,
                                                   const int2* __restrict__ edge,
                                                   const float* __restrict__ bias,
                                                   float* __restrict__ Hout) {
    int n = blockIdx.x * 4 + (threadIdx.x >> 6);
    if (n >= N_NODES) return;
    int t = threadIdx.x & 63;            // 2 channels per lane
    const float2* H2 = (const float2*)Hin;
    float disd = dis[n];
    float2 self = H2[(size_t)n * 64 + t];
    float w0 = disd * disd;              // self-loop weight
    float ax = self.x * w0, ay = self.y * w0;
    int beg = rowstart[n], end = rowstart[n + 1];
    int p = beg;
    for (; p + 1 < end; p += 2) {        // 2 independent gathers in flight
        int2 e0 = edge[p], e1 = edge[p + 1];
        float wA = __int_as_float(e0.y) * disd;
        float wB = __int_as_float(e1.y) * disd;
        float2 h0 = H2[(size_t)e0.x * 64 + t];
        float2 h1 = H2[(size_t)e1.x * 64 + t];
        ax += h0.x * wA + h1.x * wB;
        ay += h0.y * wA + h1.y * wB;
    }
    if (p < end) {
        int2 e0 = edge[p];
        float w = __int_as_float(e0.y) * disd;
        float2 hv = H2[(size_t)e0.x * 64 + t];
        ax += hv.x * w;
        ay += hv.y * w;
    }
    float2 bb = ((const float2*)bias)[t];
    float2 o;
    o.x = fmaxf(ax + bb.x, 0.f);
    o.y = fmaxf(ay + bb.y, 0.f);
    ((float2*)Hout)[(size_t)n * 64 + t] = o;
}

extern "C" void kernel_launch(void* const* d_in, const int* in_sizes, int n_in,
                              void* d_out, int out_size, void* d_ws, size_t ws_size,
                              hipStream_t stream) {
    const float* x  = (const float*)d_in[0];
    const int*   ei = (const int*)d_in[1];   // int32 per harness contract
    const float* W1 = (const float*)d_in[2];
    const float* b1 = (const float*)d_in[3];
    const float* W2 = (const float*)d_in[4];
    const float* b2 = (const float*)d_in[5];
    float* out = (float*)d_out;

    char* ws = (char*)d_ws;
    size_t off = 0;
    auto alloc = [&](size_t bytes) -> void* {
        void* p = ws + off;
        off += (bytes + 255) & ~(size_t)255;
        return p;
    };
    int*   cnt      = (int*)alloc((size_t)N_NODES * 4);
    int*   cursor   = (int*)alloc((size_t)N_NODES * 4);
    int*   rowstart = (int*)alloc((size_t)(N_NODES + 1) * 4);
    float* dis      = (float*)alloc((size_t)N_NODES * 4);
    int*   bsum     = (int*)alloc((size_t)NSBLK * 4);
    int*   boff     = (int*)alloc((size_t)NSBLK * 4);
    int2*  edge     = (int2*)alloc((size_t)N_EDGES * 8);
    float* HA       = (float*)alloc((size_t)N_NODES * D * 4);
    float* HB       = (float*)alloc((size_t)N_NODES * D * 4);

    const int* src = ei;             // edge_index[0]
    const int* dst = ei + N_EDGES;   // edge_index[1]

    // zero cnt + cursor (adjacent allocations)
    hipMemsetAsync(cnt, 0, (size_t)((char*)rowstart - (char*)cnt), stream);

    hist_kernel<<<(N_EDGES + 255) / 256, 256, 0, stream>>>(dst, cnt);
    scan1_kernel<<<NSBLK, SBLK, 0, stream>>>(cnt, rowstart, bsum);
    scan2_kernel<<<1, SBLK, 0, stream>>>(bsum, boff, rowstart);
    scan3_kernel<<<NSBLK, SBLK, 0, stream>>>(cnt, boff, rowstart, dis);
    scatter_kernel<<<(N_EDGES + 255) / 256, 256, 0, stream>>>(src, dst, rowstart, cursor,
                                                              dis, edge);

    gemm_kernel<<<N_NODES / GEMM_ROWS, 256, 0, stream>>>(x, W1, HA);
    aggr_kernel<<<(N_NODES + 3) / 4, 256, 0, stream>>>(HA, dis, rowstart, edge, b1, HB);
    gemm_kernel<<<N_NODES / GEMM_ROWS, 256, 0, stream>>>(HB, W2, HA);
    aggr_kernel<<<(N_NODES + 3) / 4, 256, 0, stream>>>(HA, dis, rowstart, edge, b2, out);
}

// Round 4
// 305.717 us; speedup vs baseline: 1.5668x; 1.2749x over previous
//
#include <hip/hip_runtime.h>

#define N_NODES 50000
#define N_EDGES 800000
#define D 128
#define SBLK 256
#define NSBLK ((N_NODES + SBLK - 1) / SBLK)   // 196
#define GR 64                                  // gemm rows per block

typedef unsigned int uint32;
typedef unsigned short ushort16;

__device__ __forceinline__ unsigned short f2bf(float f) {   // RNE bf16
    unsigned u = __float_as_uint(f);
    u += 0x7FFFu + ((u >> 16) & 1u);
    return (unsigned short)(u >> 16);
}
__device__ __forceinline__ float bf_lo(uint32 u) { return __uint_as_float(u << 16); }
__device__ __forceinline__ float bf_hi(uint32 u) { return __uint_as_float(u & 0xFFFF0000u); }

// ---------------- degree histogram ----------------
__global__ void hist_kernel(const int* __restrict__ dst, int* __restrict__ cnt) {
    int e = blockIdx.x * blockDim.x + threadIdx.x;
    if (e < N_EDGES) {
        atomicAdd(&cnt[dst[e]], 1);
    }
}

// ---------------- hierarchical scan ----------------
__device__ __forceinline__ int block_incl_scan(int v, int t) {
    int lane = t & 63, wv = t >> 6;
    int incl = v;
    #pragma unroll
    for (int off = 1; off < 64; off <<= 1) {
        int u = __shfl_up(incl, off, 64);
        if (lane >= off) incl += u;
    }
    __shared__ int wsums[4];
    if (lane == 63) wsums[wv] = incl;
    __syncthreads();
    int add = 0;
    if (wv > 0) add += wsums[0];
    if (wv > 1) add += wsums[1];
    if (wv > 2) add += wsums[2];
    return incl + add;
}

__global__ __launch_bounds__(SBLK) void scan1_kernel(const int* __restrict__ cnt,
                                                     int* __restrict__ rowstart,
                                                     int* __restrict__ bsum) {
    int t = threadIdx.x, b = blockIdx.x;
    int i = b * SBLK + t;
    int v = (i < N_NODES) ? cnt[i] : 0;
    int incl = block_incl_scan(v, t);
    if (i < N_NODES) rowstart[i] = incl - v;
    if (t == SBLK - 1) bsum[b] = incl;
}

__global__ __launch_bounds__(SBLK) void scan2_kernel(const int* __restrict__ bsum,
                                                     int* __restrict__ boff,
                                                     int* __restrict__ rowstart) {
    int t = threadIdx.x;
    int v = (t < NSBLK) ? bsum[t] : 0;
    int incl = block_incl_scan(v, t);
    if (t < NSBLK) boff[t] = incl - v;
    if (t == SBLK - 1) rowstart[N_NODES] = incl;
}

__global__ __launch_bounds__(SBLK) void scan3_kernel(const int* __restrict__ cnt,
                                                     const int* __restrict__ boff,
                                                     int* __restrict__ rowstart,
                                                     float* __restrict__ dis) {
    int i = blockIdx.x * SBLK + threadIdx.x;
    if (i < N_NODES) {
        rowstart[i] += boff[blockIdx.x];
        dis[i] = rsqrtf((float)(cnt[i] + 1));
    }
}

// ---------------- scatter edges into CSR (packed 8B record) ----------------
__global__ void scatter_kernel(const int* __restrict__ src, const int* __restrict__ dst,
                               const int* __restrict__ rowstart, int* __restrict__ cursor,
                               const float* __restrict__ dis,
                               int2* __restrict__ edge) {
    int e = blockIdx.x * blockDim.x + threadIdx.x;
    if (e < N_EDGES) {
        int s = src[e], d = dst[e];
        int p = rowstart[d] + atomicAdd(&cursor[d], 1);
        edge[p] = make_int2(s, __float_as_int(dis[s]));
    }
}

// ---------------- Hb = bf16(X @ W): 64x128 tile, 8x4 per thread ----------------
// X k-major in LDS -> per-k reads are wave-broadcast ds_read_b128 (free).
__global__ __launch_bounds__(256) void gemm_kernel(const float* __restrict__ X,
                                                   const float* __restrict__ W,
                                                   ushort16* __restrict__ Hb) {
    __shared__ __align__(16) float Xt[D * GR];   // [k][row], 32 KB
    int t = threadIdx.x;
    int rbase = blockIdx.x * GR;
    // stage + transpose: lane owns one row, walks k. LDS writes conflict-free
    // (k uniform per instr, row = lane -> consecutive banks).
    {
        int row = t & 63;
        int srow = rbase + row;
        if (srow >= N_NODES) srow = N_NODES - 1;           // clamp (stores guarded)
        const float4* Xr4 = (const float4*)(X + (size_t)srow * D);
        #pragma unroll
        for (int it = 0; it < 8; it++) {
            int kc = (t >> 6) + it * 4;                    // 0..31
            float4 v = Xr4[kc];
            int k = kc * 4;
            Xt[(k + 0) * GR + row] = v.x;
            Xt[(k + 1) * GR + row] = v.y;
            Xt[(k + 2) * GR + row] = v.z;
            Xt[(k + 3) * GR + row] = v.w;
        }
    }
    __syncthreads();
    int cg = t & 31;          // cols 4*cg .. 4*cg+3
    int rg = t >> 5;          // rows 8*rg .. 8*rg+7
    int c0 = cg * 4;
    const float4* W4 = (const float4*)W;        // W[k][c] -> float4 idx k*32+cg
    float acc[8][4];
    #pragma unroll
    for (int i = 0; i < 8; i++)
        #pragma unroll
        for (int j = 0; j < 4; j++) acc[i][j] = 0.f;
    const float* Xk = Xt + rg * 8;
    #pragma unroll 4
    for (int k = 0; k < D; k++) {
        float4 wv = W4[k * 32 + cg];            // coalesced 512B/wave, L1/L2-hot
        float xv[8];
        *(float4*)&xv[0] = *(const float4*)(Xk + k * GR);       // broadcast b128
        *(float4*)&xv[4] = *(const float4*)(Xk + k * GR + 4);   // broadcast b128
        #pragma unroll
        for (int i = 0; i < 8; i++) {
            acc[i][0] = fmaf(xv[i], wv.x, acc[i][0]);
            acc[i][1] = fmaf(xv[i], wv.y, acc[i][1]);
            acc[i][2] = fmaf(xv[i], wv.z, acc[i][2]);
            acc[i][3] = fmaf(xv[i], wv.w, acc[i][3]);
        }
    }
    #pragma unroll
    for (int i = 0; i < 8; i++) {
        int r = rbase + rg * 8 + i;
        if (r < N_NODES) {
            ushort4 o;
            o.x = f2bf(acc[i][0]);
            o.y = f2bf(acc[i][1]);
            o.z = f2bf(acc[i][2]);
            o.w = f2bf(acc[i][3]);
            *(ushort4*)(Hb + (size_t)r * D + c0) = o;   // 8B store, coalesced
        }
    }
}

// ---------------- per-dst gather-aggregate + bias + ReLU (1 wave/node, bf16 H) ----
__global__ __launch_bounds__(256) void aggr_kernel(const uint32* __restrict__ Hb,  // [N][64] 2xbf16
                                                   const float* __restrict__ dis,
                                                   const int* __restrict__ rowstart,
                                                   const int2* __restrict__ edge,
                                                   const float* __restrict__ bias,
                                                   float* __restrict__ Hout) {     // fp32 [N][128]
    int n = blockIdx.x * 4 + (threadIdx.x >> 6);
    if (n >= N_NODES) return;
    int t = threadIdx.x & 63;            // 2 channels per lane
    float disd = dis[n];
    uint32 us = Hb[(size_t)n * 64 + t];
    float w0 = disd * disd;              // self-loop weight
    float ax = bf_lo(us) * w0, ay = bf_hi(us) * w0;
    int beg = rowstart[n], end = rowstart[n + 1];
    int p = beg;
    for (; p + 3 < end; p += 4) {        // 4 independent 256B gathers in flight
        int2 e0 = edge[p], e1 = edge[p + 1], e2 = edge[p + 2], e3 = edge[p + 3];
        uint32 u0 = Hb[(size_t)e0.x * 64 + t];
        uint32 u1 = Hb[(size_t)e1.x * 64 + t];
        uint32 u2 = Hb[(size_t)e2.x * 64 + t];
        uint32 u3 = Hb[(size_t)e3.x * 64 + t];
        float wA = __int_as_float(e0.y) * disd;
        float wB = __int_as_float(e1.y) * disd;
        float wC = __int_as_float(e2.y) * disd;
        float wD = __int_as_float(e3.y) * disd;
        ax = fmaf(bf_lo(u0), wA, ax); ay = fmaf(bf_hi(u0), wA, ay);
        ax = fmaf(bf_lo(u1), wB, ax); ay = fmaf(bf_hi(u1), wB, ay);
        ax = fmaf(bf_lo(u2), wC, ax); ay = fmaf(bf_hi(u2), wC, ay);
        ax = fmaf(bf_lo(u3), wD, ax); ay = fmaf(bf_hi(u3), wD, ay);
    }
    for (; p < end; p++) {
        int2 e0 = edge[p];
        float w = __int_as_float(e0.y) * disd;
        uint32 u0 = Hb[(size_t)e0.x * 64 + t];
        ax = fmaf(bf_lo(u0), w, ax); ay = fmaf(bf_hi(u0), w, ay);
    }
    float2 bb = ((const float2*)bias)[t];
    float2 o;
    o.x = fmaxf(ax + bb.x, 0.f);
    o.y = fmaxf(ay + bb.y, 0.f);
    ((float2*)Hout)[(size_t)n * 64 + t] = o;    // 512B/row coalesced
}

extern "C" void kernel_launch(void* const* d_in, const int* in_sizes, int n_in,
                              void* d_out, int out_size, void* d_ws, size_t ws_size,
                              hipStream_t stream) {
    const float* x  = (const float*)d_in[0];
    const int*   ei = (const int*)d_in[1];   // int32 per harness contract
    const float* W1 = (const float*)d_in[2];
    const float* b1 = (const float*)d_in[3];
    const float* W2 = (const float*)d_in[4];
    const float* b2 = (const float*)d_in[5];
    float* out = (float*)d_out;

    char* ws = (char*)d_ws;
    size_t off = 0;
    auto alloc = [&](size_t bytes) -> void* {
        void* p = ws + off;
        off += (bytes + 255) & ~(size_t)255;
        return p;
    };
    int*   cnt      = (int*)alloc((size_t)N_NODES * 4);
    int*   cursor   = (int*)alloc((size_t)N_NODES * 4);
    int*   rowstart = (int*)alloc((size_t)(N_NODES + 1) * 4);
    float* dis      = (float*)alloc((size_t)N_NODES * 4);
    int*   bsum     = (int*)alloc((size_t)NSBLK * 4);
    int*   boff     = (int*)alloc((size_t)NSBLK * 4);
    int2*  edge     = (int2*)alloc((size_t)N_EDGES * 8);
    ushort16* Hb    = (ushort16*)alloc((size_t)N_NODES * D * 2);  // bf16 H
    float* HO1      = (float*)alloc((size_t)N_NODES * D * 4);     // layer-1 out fp32

    const int* src = ei;             // edge_index[0]
    const int* dst = ei + N_EDGES;   // edge_index[1]

    hipMemsetAsync(cnt, 0, (size_t)((char*)rowstart - (char*)cnt), stream);

    hist_kernel<<<(N_EDGES + 255) / 256, 256, 0, stream>>>(dst, cnt);
    scan1_kernel<<<NSBLK, SBLK, 0, stream>>>(cnt, rowstart, bsum);
    scan2_kernel<<<1, SBLK, 0, stream>>>(bsum, boff, rowstart);
    scan3_kernel<<<NSBLK, SBLK, 0, stream>>>(cnt, boff, rowstart, dis);
    scatter_kernel<<<(N_EDGES + 255) / 256, 256, 0, stream>>>(src, dst, rowstart, cursor,
                                                              dis, edge);

    gemm_kernel<<<(N_NODES + GR - 1) / GR, 256, 0, stream>>>(x, W1, Hb);
    aggr_kernel<<<(N_NODES + 3) / 4, 256, 0, stream>>>((const uint32*)Hb, dis, rowstart,
                                                       edge, b1, HO1);
    gemm_kernel<<<(N_NODES + GR - 1) / GR, 256, 0, stream>>>(HO1, W2, Hb);
    aggr_kernel<<<(N_NODES + 3) / 4, 256, 0, stream>>>((const uint32*)Hb, dis, rowstart,
                                                       edge, b2, out);
}

// Round 5
// 295.546 us; speedup vs baseline: 1.6207x; 1.0344x over previous
//
#include <hip/hip_runtime.h>

#define N_NODES 50000
#define N_EDGES 800000
#define D 128
#define SBLK 256
#define NSBLK ((N_NODES + SBLK - 1) / SBLK)   // 196

typedef unsigned int uint32;
typedef unsigned short ushort;
typedef __attribute__((ext_vector_type(8))) short s8v;   // 8 x bf16 bits (4 VGPR)
typedef __attribute__((ext_vector_type(4))) float f4v;   // MFMA accumulator

__device__ __forceinline__ ushort f2bf(float f) {   // RNE bf16
    unsigned u = __float_as_uint(f);
    u += 0x7FFFu + ((u >> 16) & 1u);
    return (ushort)(u >> 16);
}
__device__ __forceinline__ float bf_lo(uint32 u) { return __uint_as_float(u << 16); }
__device__ __forceinline__ float bf_hi(uint32 u) { return __uint_as_float(u & 0xFFFF0000u); }

// ---------------- degree histogram ----------------
__global__ void hist_kernel(const int* __restrict__ dst, int* __restrict__ cnt) {
    int e = blockIdx.x * blockDim.x + threadIdx.x;
    if (e < N_EDGES) atomicAdd(&cnt[dst[e]], 1);
}

// ---------------- hierarchical scan ----------------
__device__ __forceinline__ int block_incl_scan(int v, int t) {
    int lane = t & 63, wv = t >> 6;
    int incl = v;
    #pragma unroll
    for (int off = 1; off < 64; off <<= 1) {
        int u = __shfl_up(incl, off, 64);
        if (lane >= off) incl += u;
    }
    __shared__ int wsums[4];
    if (lane == 63) wsums[wv] = incl;
    __syncthreads();
    int add = 0;
    if (wv > 0) add += wsums[0];
    if (wv > 1) add += wsums[1];
    if (wv > 2) add += wsums[2];
    return incl + add;
}

__global__ __launch_bounds__(SBLK) void scan1_kernel(const int* __restrict__ cnt,
                                                     int* __restrict__ rowstart,
                                                     int* __restrict__ bsum) {
    int t = threadIdx.x, b = blockIdx.x;
    int i = b * SBLK + t;
    int v = (i < N_NODES) ? cnt[i] : 0;
    int incl = block_incl_scan(v, t);
    if (i < N_NODES) rowstart[i] = incl - v;
    if (t == SBLK - 1) bsum[b] = incl;
}

__global__ __launch_bounds__(SBLK) void scan2_kernel(const int* __restrict__ bsum,
                                                     int* __restrict__ boff,
                                                     int* __restrict__ rowstart) {
    int t = threadIdx.x;
    int v = (t < NSBLK) ? bsum[t] : 0;
    int incl = block_incl_scan(v, t);
    if (t < NSBLK) boff[t] = incl - v;
    if (t == SBLK - 1) rowstart[N_NODES] = incl;
}

// phase 3: finalize rowstart, preload scatter cursor, dis = rsqrt(deg+1)
__global__ __launch_bounds__(SBLK) void scan3_kernel(const int* __restrict__ cnt,
                                                     const int* __restrict__ boff,
                                                     int* __restrict__ rowstart,
                                                     int* __restrict__ cursor,
                                                     float* __restrict__ dis) {
    int i = blockIdx.x * SBLK + threadIdx.x;
    if (i < N_NODES) {
        int rs = rowstart[i] + boff[blockIdx.x];
        rowstart[i] = rs;
        cursor[i] = rs;                         // scatter position = atomicAdd here
        dis[i] = rsqrtf((float)(cnt[i] + 1));
    }
}

// ---------------- scatter edges into CSR (packed 8B record, cursor-direct) -------
__global__ void scatter_kernel(const int* __restrict__ src, const int* __restrict__ dst,
                               int* __restrict__ cursor, const float* __restrict__ dis,
                               int2* __restrict__ edge) {
    int e = blockIdx.x * blockDim.x + threadIdx.x;
    if (e < N_EDGES) {
        int s = src[e], d = dst[e];
        int p = atomicAdd(&cursor[d], 1);
        edge[p] = make_int2(s, __float_as_int(dis[s]));
    }
}

// ---------------- W^T bf16 prep: Wt[n][k] from W[k][n] ----------------
__global__ __launch_bounds__(256) void wprep_kernel(const float* __restrict__ W1,
                                                    const float* __restrict__ W2,
                                                    ushort* __restrict__ W1t,
                                                    ushort* __restrict__ W2t) {
    const float* W = blockIdx.x ? W2 : W1;
    ushort* Wt = blockIdx.x ? W2t : W1t;
    int t = threadIdx.x;
    #pragma unroll
    for (int it = 0; it < 16; it++) {
        int fid = t + it * 256;          // float4 id 0..4095
        int k = fid >> 5;                // 0..127
        int n0 = (fid & 31) * 4;
        float4 w = ((const float4*)W)[fid];
        Wt[(n0 + 0) * D + k] = f2bf(w.x);
        Wt[(n0 + 1) * D + k] = f2bf(w.y);
        Wt[(n0 + 2) * D + k] = f2bf(w.z);
        Wt[(n0 + 3) * D + k] = f2bf(w.w);
    }
}

// ---------------- Hb = bf16(X @ W) via MFMA 16x16x32 bf16 ----------------
// Block tile 128x128: 4 waves, each wave 32 rows (2 m-tiles) x 128 cols (8 n-tiles).
// A: global fp32 -> cvt bf16 in regs. B: global bf16 W^T (32KB, L1-hot), per-lane
// contiguous b128. C: LDS transpose epilogue -> coalesced bf16 stores.
__global__ __launch_bounds__(256) void gemm_mfma(const float* __restrict__ X,
                                                 const ushort* __restrict__ Wt,
                                                 ushort* __restrict__ Hb) {
    __shared__ ushort Cs[128 * 136];     // 34.8 KB, +8 pad vs bank stride
    int t = threadIdx.x;
    int wv = t >> 6, lane = t & 63;
    int q = lane >> 4, m = lane & 15;
    int rbase = blockIdx.x * 128 + wv * 32;
    f4v zero = {0.f, 0.f, 0.f, 0.f};
    f4v acc[2][8];
    #pragma unroll
    for (int mt = 0; mt < 2; mt++)
        #pragma unroll
        for (int n = 0; n < 8; n++) acc[mt][n] = zero;

    #pragma unroll
    for (int kt = 0; kt < 4; kt++) {
        int k0 = kt * 32 + q * 8;        // lane's K-slice
        s8v a[2];
        #pragma unroll
        for (int mt = 0; mt < 2; mt++) {
            int row = rbase + mt * 16 + m;
            if (row >= N_NODES) row = N_NODES - 1;     // clamp; stores guarded
            const float* xp = X + (size_t)row * D + k0;
            float4 u0 = *(const float4*)xp;
            float4 u1 = *(const float4*)(xp + 4);
            s8v av;
            av[0] = (short)f2bf(u0.x); av[1] = (short)f2bf(u0.y);
            av[2] = (short)f2bf(u0.z); av[3] = (short)f2bf(u0.w);
            av[4] = (short)f2bf(u1.x); av[5] = (short)f2bf(u1.y);
            av[6] = (short)f2bf(u1.z); av[7] = (short)f2bf(u1.w);
            a[mt] = av;
        }
        #pragma unroll
        for (int n = 0; n < 8; n++) {
            s8v b = *(const s8v*)(Wt + (size_t)(n * 16 + m) * D + k0);  // B[n][k] contig
            acc[0][n] = __builtin_amdgcn_mfma_f32_16x16x32_bf16(a[0], b, acc[0][n], 0, 0, 0);
            acc[1][n] = __builtin_amdgcn_mfma_f32_16x16x32_bf16(a[1], b, acc[1][n], 0, 0, 0);
        }
    }
    // epilogue: C/D layout col=lane&15, row=quad*4+reg  (m89-verified)
    #pragma unroll
    for (int mt = 0; mt < 2; mt++)
        #pragma unroll
        for (int n = 0; n < 8; n++)
            #pragma unroll
            for (int r = 0; r < 4; r++) {
                int row = wv * 32 + mt * 16 + q * 4 + r;
                Cs[row * 136 + n * 16 + m] = f2bf(acc[mt][n][r]);
            }
    __syncthreads();
    int gbase = blockIdx.x * 128;
    #pragma unroll
    for (int it = 0; it < 8; it++) {
        int cid = t + it * 256;          // 2048 chunks of 8 bf16
        int row = cid >> 4, off = (cid & 15) * 8;
        int grow = gbase + row;
        if (grow < N_NODES) {
            s8v v = *(const s8v*)(Cs + row * 136 + off);
            *(s8v*)(Hb + (size_t)grow * D + off) = v;
        }
    }
}

// ---------------- per-dst gather-aggregate + bias + ReLU (1 wave/node, bf16 H) ----
__global__ __launch_bounds__(256) void aggr_kernel(const uint32* __restrict__ Hb,
                                                   const float* __restrict__ dis,
                                                   const int* __restrict__ rowstart,
                                                   const int2* __restrict__ edge,
                                                   const float* __restrict__ bias,
                                                   float* __restrict__ Hout) {
    int n = blockIdx.x * 4 + (threadIdx.x >> 6);
    if (n >= N_NODES) return;
    int t = threadIdx.x & 63;            // 2 channels per lane
    float disd = dis[n];
    uint32 us = Hb[(size_t)n * 64 + t];
    float w0 = disd * disd;
    float ax = bf_lo(us) * w0, ay = bf_hi(us) * w0;
    int beg = rowstart[n], end = rowstart[n + 1];
    int p = beg;
    for (; p + 7 < end; p += 8) {        // 8 independent 256B gathers in flight
        int2 e0 = edge[p + 0], e1 = edge[p + 1], e2 = edge[p + 2], e3 = edge[p + 3];
        int2 e4 = edge[p + 4], e5 = edge[p + 5], e6 = edge[p + 6], e7 = edge[p + 7];
        uint32 u0 = Hb[(size_t)e0.x * 64 + t];
        uint32 u1 = Hb[(size_t)e1.x * 64 + t];
        uint32 u2 = Hb[(size_t)e2.x * 64 + t];
        uint32 u3 = Hb[(size_t)e3.x * 64 + t];
        uint32 u4 = Hb[(size_t)e4.x * 64 + t];
        uint32 u5 = Hb[(size_t)e5.x * 64 + t];
        uint32 u6 = Hb[(size_t)e6.x * 64 + t];
        uint32 u7 = Hb[(size_t)e7.x * 64 + t];
        float wA = __int_as_float(e0.y) * disd, wB = __int_as_float(e1.y) * disd;
        float wC = __int_as_float(e2.y) * disd, wD = __int_as_float(e3.y) * disd;
        float wE = __int_as_float(e4.y) * disd, wF = __int_as_float(e5.y) * disd;
        float wG = __int_as_float(e6.y) * disd, wH = __int_as_float(e7.y) * disd;
        ax = fmaf(bf_lo(u0), wA, ax); ay = fmaf(bf_hi(u0), wA, ay);
        ax = fmaf(bf_lo(u1), wB, ax); ay = fmaf(bf_hi(u1), wB, ay);
        ax = fmaf(bf_lo(u2), wC, ax); ay = fmaf(bf_hi(u2), wC, ay);
        ax = fmaf(bf_lo(u3), wD, ax); ay = fmaf(bf_hi(u3), wD, ay);
        ax = fmaf(bf_lo(u4), wE, ax); ay = fmaf(bf_hi(u4), wE, ay);
        ax = fmaf(bf_lo(u5), wF, ax); ay = fmaf(bf_hi(u5), wF, ay);
        ax = fmaf(bf_lo(u6), wG, ax); ay = fmaf(bf_hi(u6), wG, ay);
        ax = fmaf(bf_lo(u7), wH, ax); ay = fmaf(bf_hi(u7), wH, ay);
    }
    for (; p < end; p++) {
        int2 e0 = edge[p];
        float w = __int_as_float(e0.y) * disd;
        uint32 u0 = Hb[(size_t)e0.x * 64 + t];
        ax = fmaf(bf_lo(u0), w, ax); ay = fmaf(bf_hi(u0), w, ay);
    }
    float2 bb = ((const float2*)bias)[t];
    float2 o;
    o.x = fmaxf(ax + bb.x, 0.f);
    o.y = fmaxf(ay + bb.y, 0.f);
    ((float2*)Hout)[(size_t)n * 64 + t] = o;
}

extern "C" void kernel_launch(void* const* d_in, const int* in_sizes, int n_in,
                              void* d_out, int out_size, void* d_ws, size_t ws_size,
                              hipStream_t stream) {
    const float* x  = (const float*)d_in[0];
    const int*   ei = (const int*)d_in[1];   // int32 per harness contract
    const float* W1 = (const float*)d_in[2];
    const float* b1 = (const float*)d_in[3];
    const float* W2 = (const float*)d_in[4];
    const float* b2 = (const float*)d_in[5];
    float* out = (float*)d_out;

    char* ws = (char*)d_ws;
    size_t off = 0;
    auto alloc = [&](size_t bytes) -> void* {
        void* p = ws + off;
        off += (bytes + 255) & ~(size_t)255;
        return p;
    };
    int*    cnt      = (int*)alloc((size_t)N_NODES * 4);
    int*    cursor   = (int*)alloc((size_t)N_NODES * 4);
    int*    rowstart = (int*)alloc((size_t)(N_NODES + 1) * 4);
    float*  dis      = (float*)alloc((size_t)N_NODES * 4);
    int*    bsum     = (int*)alloc((size_t)NSBLK * 4);
    int*    boff     = (int*)alloc((size_t)NSBLK * 4);
    int2*   edge     = (int2*)alloc((size_t)N_EDGES * 8);
    ushort* Hb       = (ushort*)alloc((size_t)N_NODES * D * 2);   // bf16 gemm out
    float*  HO1      = (float*)alloc((size_t)N_NODES * D * 4);    // layer-1 out fp32
    ushort* W1t      = (ushort*)alloc((size_t)D * D * 2);         // bf16 W^T
    ushort* W2t      = (ushort*)alloc((size_t)D * D * 2);

    const int* src = ei;             // edge_index[0]
    const int* dst = ei + N_EDGES;   // edge_index[1]

    hipMemsetAsync(cnt, 0, (size_t)N_NODES * 4, stream);

    wprep_kernel<<<2, 256, 0, stream>>>(W1, W2, W1t, W2t);
    hist_kernel<<<(N_EDGES + 255) / 256, 256, 0, stream>>>(dst, cnt);
    scan1_kernel<<<NSBLK, SBLK, 0, stream>>>(cnt, rowstart, bsum);
    scan2_kernel<<<1, SBLK, 0, stream>>>(bsum, boff, rowstart);
    scan3_kernel<<<NSBLK, SBLK, 0, stream>>>(cnt, boff, rowstart, cursor, dis);
    scatter_kernel<<<(N_EDGES + 255) / 256, 256, 0, stream>>>(src, dst, cursor, dis, edge);

    gemm_mfma<<<(N_NODES + 127) / 128, 256, 0, stream>>>(x, W1t, Hb);
    aggr_kernel<<<(N_NODES + 3) / 4, 256, 0, stream>>>((const uint32*)Hb, dis, rowstart,
                                                       edge, b1, HO1);
    gemm_mfma<<<(N_NODES + 127) / 128, 256, 0, stream>>>(HO1, W2t, Hb);
    aggr_kernel<<<(N_NODES + 3) / 4, 256, 0, stream>>>((const uint32*)Hb, dis, rowstart,
                                                       edge, b2, out);
}

// Round 6
// 235.017 us; speedup vs baseline: 2.0382x; 1.2576x over previous
//
#include <hip/hip_runtime.h>

#define N_NODES 50000
#define N_EDGES 800000
#define D 128
#define NB 196          // chunk blocks for edge phases
#define CHUNK 4096      // edges per chunk block (196*4096 >= 800000)
#define NBKT 196        // buckets = dst>>8 (50000/256 -> 196)
#define LHM (NBKT * NB) // hist matrix length 38416
#define NSB 151         // ceil(LHM/256)

typedef unsigned int uint32;
typedef unsigned short ushort;
typedef __attribute__((ext_vector_type(8))) short s8v;   // 8 x bf16 bits
typedef __attribute__((ext_vector_type(4))) float f4v;   // MFMA accumulator

__device__ __forceinline__ ushort f2bf(float f) {   // RNE bf16
    unsigned u = __float_as_uint(f);
    u += 0x7FFFu + ((u >> 16) & 1u);
    return (ushort)(u >> 16);
}
__device__ __forceinline__ float bf_lo(uint32 u) { return __uint_as_float(u << 16); }
__device__ __forceinline__ float bf_hi(uint32 u) { return __uint_as_float(u & 0xFFFF0000u); }

// ---- block-wide inclusive scan helper (256 threads = 4 waves) ----
__device__ __forceinline__ int block_incl_scan(int v, int t) {
    int lane = t & 63, wv = t >> 6;
    int incl = v;
    #pragma unroll
    for (int off = 1; off < 64; off <<= 1) {
        int u = __shfl_up(incl, off, 64);
        if (lane >= off) incl += u;
    }
    __shared__ int wsums[4];
    if (lane == 63) wsums[wv] = incl;
    __syncthreads();
    int add = 0;
    if (wv > 0) add += wsums[0];
    if (wv > 1) add += wsums[1];
    if (wv > 2) add += wsums[2];
    return incl + add;
}

// ---------------- Phase A: per-chunk bucket histogram (LDS atomics only) --------
__global__ __launch_bounds__(256) void phaseA_kernel(const int* __restrict__ dst,
                                                     int* __restrict__ histM) {
    __shared__ int cnt[NBKT];
    int t = threadIdx.x, blk = blockIdx.x;
    if (t < NBKT) cnt[t] = 0;
    __syncthreads();
    int e0 = blk * CHUNK;
    for (int i = t; i < CHUNK; i += 256) {
        int e = e0 + i;
        if (e < N_EDGES) atomicAdd(&cnt[dst[e] >> 8], 1);
    }
    __syncthreads();
    if (t < NBKT) histM[t * NB + blk] = cnt[t];   // bucket-major, block-minor
}

// ---------------- Phase B: hierarchical scan over LHM ints ----------------
__global__ __launch_bounds__(256) void scan1g(const int* __restrict__ in,
                                              int* __restrict__ out,
                                              int* __restrict__ bsum) {
    int t = threadIdx.x, blk = blockIdx.x;
    int i = blk * 256 + t;
    int v = (i < LHM) ? in[i] : 0;
    int incl = block_incl_scan(v, t);
    if (i < LHM) out[i] = incl - v;
    if (t == 255) bsum[blk] = incl;
}
__global__ __launch_bounds__(256) void scan2g(const int* __restrict__ bsum,
                                              int* __restrict__ boff) {
    int t = threadIdx.x;
    int v = (t < NSB) ? bsum[t] : 0;
    int incl = block_incl_scan(v, t);
    if (t < NSB) boff[t] = incl - v;
}
__global__ __launch_bounds__(256) void scan3g(int* __restrict__ out,
                                              const int* __restrict__ boff) {
    int i = blockIdx.x * 256 + threadIdx.x;
    if (i < LHM) out[i] += boff[blockIdx.x];
}

// ---------------- Phase C: partition edges into bucket-major order --------------
__global__ __launch_bounds__(256) void phaseC_kernel(const int* __restrict__ src,
                                                     const int* __restrict__ dst,
                                                     const int* __restrict__ base,
                                                     uint32* __restrict__ edgeTmp) {
    __shared__ int cur[NBKT];
    int t = threadIdx.x, blk = blockIdx.x;
    if (t < NBKT) cur[t] = base[t * NB + blk];
    __syncthreads();
    int e0 = blk * CHUNK;
    for (int i = t; i < CHUNK; i += 256) {
        int e = e0 + i;
        if (e < N_EDGES) {
            uint32 s = (uint32)src[e], d = (uint32)dst[e];
            int p = atomicAdd(&cur[d >> 8], 1);      // LDS atomic
            edgeTmp[p] = (s << 16) | d;              // both < 65536
        }
    }
}

// ---------------- Phase D: per-bucket counting sort + rowstart + dis ------------
__global__ __launch_bounds__(256) void phaseD_kernel(const uint32* __restrict__ edgeTmp,
                                                     const int* __restrict__ base,
                                                     int* __restrict__ rowstart,
                                                     float* __restrict__ dis,
                                                     ushort* __restrict__ e16) {
    __shared__ int cnt[256];
    __shared__ int cur[256];
    int t = threadIdx.x, b = blockIdx.x;
    int beg = base[b * NB];
    int end = (b == NBKT - 1) ? N_EDGES : base[(b + 1) * NB];
    cnt[t] = 0;
    __syncthreads();
    for (int p = beg + t; p < end; p += 256)
        atomicAdd(&cnt[edgeTmp[p] & 255], 1);
    __syncthreads();
    int c = cnt[t];
    int incl = block_incl_scan(c, t);
    int excl = incl - c;
    int node = b * 256 + t;
    if (node <= N_NODES) rowstart[node] = beg + excl;   // node==N -> beg+size = E
    if (node < N_NODES) dis[node] = rsqrtf((float)(c + 1));
    cur[t] = excl;
    __syncthreads();
    for (int p = beg + t; p < end; p += 256) {
        uint32 u = edgeTmp[p];
        int r = atomicAdd(&cur[u & 255], 1);            // LDS atomic
        e16[beg + r] = (ushort)(u >> 16);               // in-bucket region, L2-local
    }
}

// ---------------- W^T bf16 prep: Wt[n][k] from W[k][n] ----------------
__global__ __launch_bounds__(256) void wprep_kernel(const float* __restrict__ W1,
                                                    const float* __restrict__ W2,
                                                    ushort* __restrict__ W1t,
                                                    ushort* __restrict__ W2t) {
    const float* W = blockIdx.x ? W2 : W1;
    ushort* Wt = blockIdx.x ? W2t : W1t;
    int t = threadIdx.x;
    #pragma unroll
    for (int it = 0; it < 16; it++) {
        int fid = t + it * 256;
        int k = fid >> 5;
        int n0 = (fid & 31) * 4;
        float4 w = ((const float4*)W)[fid];
        Wt[(n0 + 0) * D + k] = f2bf(w.x);
        Wt[(n0 + 1) * D + k] = f2bf(w.y);
        Wt[(n0 + 2) * D + k] = f2bf(w.z);
        Wt[(n0 + 3) * D + k] = f2bf(w.w);
    }
}

// ---------------- Hb = bf16(dis[r] * (X @ W)) via MFMA 16x16x32 bf16 ------------
__global__ __launch_bounds__(256) void gemm_mfma(const float* __restrict__ X,
                                                 const ushort* __restrict__ Wt,
                                                 const float* __restrict__ dis,
                                                 ushort* __restrict__ Hb) {
    __shared__ ushort Cs[128 * 136];
    int t = threadIdx.x;
    int wv = t >> 6, lane = t & 63;
    int q = lane >> 4, m = lane & 15;
    int rbase = blockIdx.x * 128 + wv * 32;
    f4v zero = {0.f, 0.f, 0.f, 0.f};
    f4v acc[2][8];
    #pragma unroll
    for (int mt = 0; mt < 2; mt++)
        #pragma unroll
        for (int n = 0; n < 8; n++) acc[mt][n] = zero;

    #pragma unroll
    for (int kt = 0; kt < 4; kt++) {
        int k0 = kt * 32 + q * 8;
        s8v a[2];
        #pragma unroll
        for (int mt = 0; mt < 2; mt++) {
            int row = rbase + mt * 16 + m;
            if (row >= N_NODES) row = N_NODES - 1;
            const float* xp = X + (size_t)row * D + k0;
            float4 u0 = *(const float4*)xp;
            float4 u1 = *(const float4*)(xp + 4);
            s8v av;
            av[0] = (short)f2bf(u0.x); av[1] = (short)f2bf(u0.y);
            av[2] = (short)f2bf(u0.z); av[3] = (short)f2bf(u0.w);
            av[4] = (short)f2bf(u1.x); av[5] = (short)f2bf(u1.y);
            av[6] = (short)f2bf(u1.z); av[7] = (short)f2bf(u1.w);
            a[mt] = av;
        }
        #pragma unroll
        for (int n = 0; n < 8; n++) {
            s8v b = *(const s8v*)(Wt + (size_t)(n * 16 + m) * D + k0);
            acc[0][n] = __builtin_amdgcn_mfma_f32_16x16x32_bf16(a[0], b, acc[0][n], 0, 0, 0);
            acc[1][n] = __builtin_amdgcn_mfma_f32_16x16x32_bf16(a[1], b, acc[1][n], 0, 0, 0);
        }
    }
    // dis scale per output row (fused normalization)
    float disv[2][4];
    #pragma unroll
    for (int mt = 0; mt < 2; mt++)
        #pragma unroll
        for (int r = 0; r < 4; r++) {
            int row = rbase + mt * 16 + q * 4 + r;
            if (row >= N_NODES) row = N_NODES - 1;
            disv[mt][r] = dis[row];
        }
    #pragma unroll
    for (int mt = 0; mt < 2; mt++)
        #pragma unroll
        for (int n = 0; n < 8; n++)
            #pragma unroll
            for (int r = 0; r < 4; r++) {
                int row = wv * 32 + mt * 16 + q * 4 + r;
                Cs[row * 136 + n * 16 + m] = f2bf(acc[mt][n][r] * disv[mt][r]);
            }
    __syncthreads();
    int gbase = blockIdx.x * 128;
    #pragma unroll
    for (int it = 0; it < 8; it++) {
        int cid = t + it * 256;
        int row = cid >> 4, off = (cid & 15) * 8;
        int grow = gbase + row;
        if (grow < N_NODES) {
            s8v v = *(const s8v*)(Cs + row * 136 + off);
            *(s8v*)(Hb + (size_t)grow * D + off) = v;
        }
    }
}

// ---------------- per-dst aggregate: out = relu(dis[n]*(Hb[n]+sum Hb[src])+b) ----
__global__ __launch_bounds__(256) void aggr_kernel(const uint32* __restrict__ Hb,
                                                   const float* __restrict__ dis,
                                                   const int* __restrict__ rowstart,
                                                   const ushort* __restrict__ e16,
                                                   const float* __restrict__ bias,
                                                   float* __restrict__ Hout) {
    int n = blockIdx.x * 4 + (threadIdx.x >> 6);
    if (n >= N_NODES) return;
    int t = threadIdx.x & 63;            // 2 channels per lane
    float dn = dis[n];
    uint32 us = Hb[(size_t)n * 64 + t];
    float ax = bf_lo(us), ay = bf_hi(us);        // self term (weight folded in)
    int beg = rowstart[n], end = rowstart[n + 1];
    int p = beg;
    for (; p + 7 < end; p += 8) {        // 8 independent 256B gathers in flight
        int s0 = e16[p + 0], s1 = e16[p + 1], s2 = e16[p + 2], s3 = e16[p + 3];
        int s4 = e16[p + 4], s5 = e16[p + 5], s6 = e16[p + 6], s7 = e16[p + 7];
        uint32 u0 = Hb[(size_t)s0 * 64 + t];
        uint32 u1 = Hb[(size_t)s1 * 64 + t];
        uint32 u2 = Hb[(size_t)s2 * 64 + t];
        uint32 u3 = Hb[(size_t)s3 * 64 + t];
        uint32 u4 = Hb[(size_t)s4 * 64 + t];
        uint32 u5 = Hb[(size_t)s5 * 64 + t];
        uint32 u6 = Hb[(size_t)s6 * 64 + t];
        uint32 u7 = Hb[(size_t)s7 * 64 + t];
        ax += bf_lo(u0) + bf_lo(u1) + bf_lo(u2) + bf_lo(u3)
            + bf_lo(u4) + bf_lo(u5) + bf_lo(u6) + bf_lo(u7);
        ay += bf_hi(u0) + bf_hi(u1) + bf_hi(u2) + bf_hi(u3)
            + bf_hi(u4) + bf_hi(u5) + bf_hi(u6) + bf_hi(u7);
    }
    for (; p < end; p++) {
        uint32 u0 = Hb[(size_t)e16[p] * 64 + t];
        ax += bf_lo(u0); ay += bf_hi(u0);
    }
    float2 bb = ((const float2*)bias)[t];
    float2 o;
    o.x = fmaxf(fmaf(dn, ax, bb.x), 0.f);
    o.y = fmaxf(fmaf(dn, ay, bb.y), 0.f);
    ((float2*)Hout)[(size_t)n * 64 + t] = o;
}

extern "C" void kernel_launch(void* const* d_in, const int* in_sizes, int n_in,
                              void* d_out, int out_size, void* d_ws, size_t ws_size,
                              hipStream_t stream) {
    const float* x  = (const float*)d_in[0];
    const int*   ei = (const int*)d_in[1];   // int32 per harness contract
    const float* W1 = (const float*)d_in[2];
    const float* b1 = (const float*)d_in[3];
    const float* W2 = (const float*)d_in[4];
    const float* b2 = (const float*)d_in[5];
    float* out = (float*)d_out;

    char* ws = (char*)d_ws;
    size_t off = 0;
    auto alloc = [&](size_t bytes) -> void* {
        void* p = ws + off;
        off += (bytes + 255) & ~(size_t)255;
        return p;
    };
    int*    histM    = (int*)alloc((size_t)LHM * 4);
    int*    base     = (int*)alloc((size_t)LHM * 4);
    int*    bsum     = (int*)alloc(256 * 4);
    int*    boff     = (int*)alloc(256 * 4);
    int*    rowstart = (int*)alloc((size_t)(N_NODES + 1) * 4);
    float*  dis      = (float*)alloc((size_t)N_NODES * 4);
    uint32* edgeTmp  = (uint32*)alloc((size_t)N_EDGES * 4);
    ushort* e16      = (ushort*)alloc((size_t)N_EDGES * 2);
    ushort* Hb       = (ushort*)alloc((size_t)N_NODES * D * 2);
    float*  HO1      = (float*)alloc((size_t)N_NODES * D * 4);
    ushort* W1t      = (ushort*)alloc((size_t)D * D * 2);
    ushort* W2t      = (ushort*)alloc((size_t)D * D * 2);

    const int* src = ei;             // edge_index[0]
    const int* dst = ei + N_EDGES;   // edge_index[1]

    wprep_kernel<<<2, 256, 0, stream>>>(W1, W2, W1t, W2t);
    phaseA_kernel<<<NB, 256, 0, stream>>>(dst, histM);
    scan1g<<<NSB, 256, 0, stream>>>(histM, base, bsum);
    scan2g<<<1, 256, 0, stream>>>(bsum, boff);
    scan3g<<<NSB, 256, 0, stream>>>(base, boff);
    phaseC_kernel<<<NB, 256, 0, stream>>>(src, dst, base, edgeTmp);
    phaseD_kernel<<<NBKT, 256, 0, stream>>>(edgeTmp, base, rowstart, dis, e16);

    gemm_mfma<<<(N_NODES + 127) / 128, 256, 0, stream>>>(x, W1t, dis, Hb);
    aggr_kernel<<<(N_NODES + 3) / 4, 256, 0, stream>>>((const uint32*)Hb, dis, rowstart,
                                                       e16, b1, HO1);
    gemm_mfma<<<(N_NODES + 127) / 128, 256, 0, stream>>>(HO1, W2t, dis, Hb);
    aggr_kernel<<<(N_NODES + 3) / 4, 256, 0, stream>>>((const uint32*)Hb, dis, rowstart,
                                                       e16, b2, out);
}

// Round 7
// 216.428 us; speedup vs baseline: 2.2132x; 1.0859x over previous
//
#include <hip/hip_runtime.h>

#define N_NODES 50000
#define N_EDGES 800000
#define D 128
#define NB 196          // chunk blocks for edge phases
#define CHUNK 4096      // edges per chunk block (196*4096 >= 800000)
#define NBKT 196        // buckets = dst>>8
#define LHM (NBKT * NB) // hist matrix length 38416
#define NSB 151         // ceil(LHM/256)

typedef unsigned int uint32;
typedef unsigned short ushort;
typedef __attribute__((ext_vector_type(8))) short s8v;   // 8 x bf16 bits
typedef __attribute__((ext_vector_type(4))) float f4v;   // MFMA accumulator

__device__ __forceinline__ ushort f2bf(float f) {   // RNE bf16
    unsigned u = __float_as_uint(f);
    u += 0x7FFFu + ((u >> 16) & 1u);
    return (ushort)(u >> 16);
}
__device__ __forceinline__ float bf_lo(uint32 u) { return __uint_as_float(u << 16); }
__device__ __forceinline__ float bf_hi(uint32 u) { return __uint_as_float(u & 0xFFFF0000u); }

// ---- block-wide inclusive scan helper (256 threads = 4 waves) ----
__device__ __forceinline__ int block_incl_scan(int v, int t) {
    int lane = t & 63, wv = t >> 6;
    int incl = v;
    #pragma unroll
    for (int off = 1; off < 64; off <<= 1) {
        int u = __shfl_up(incl, off, 64);
        if (lane >= off) incl += u;
    }
    __shared__ int wsums[4];
    if (lane == 63) wsums[wv] = incl;
    __syncthreads();
    int add = 0;
    if (wv > 0) add += wsums[0];
    if (wv > 1) add += wsums[1];
    if (wv > 2) add += wsums[2];
    return incl + add;
}

// ---------------- Phase A: per-chunk bucket histogram (LDS atomics only) --------
__global__ __launch_bounds__(256) void phaseA_kernel(const int* __restrict__ dst,
                                                     int* __restrict__ histM) {
    __shared__ int cnt[NBKT];
    int t = threadIdx.x, blk = blockIdx.x;
    if (t < NBKT) cnt[t] = 0;
    __syncthreads();
    int e0 = blk * CHUNK;
    for (int i = t; i < CHUNK; i += 256) {
        int e = e0 + i;
        if (e < N_EDGES) atomicAdd(&cnt[dst[e] >> 8], 1);
    }
    __syncthreads();
    if (t < NBKT) histM[t * NB + blk] = cnt[t];   // bucket-major, block-minor
}

// ---------------- Phase B: hierarchical scan over LHM ints ----------------
__global__ __launch_bounds__(256) void scan1g(const int* __restrict__ in,
                                              int* __restrict__ out,
                                              int* __restrict__ bsum) {
    int t = threadIdx.x, blk = blockIdx.x;
    int i = blk * 256 + t;
    int v = (i < LHM) ? in[i] : 0;
    int incl = block_incl_scan(v, t);
    if (i < LHM) out[i] = incl - v;
    if (t == 255) bsum[blk] = incl;
}
__global__ __launch_bounds__(256) void scan2g(const int* __restrict__ bsum,
                                              int* __restrict__ boff) {
    int t = threadIdx.x;
    int v = (t < NSB) ? bsum[t] : 0;
    int incl = block_incl_scan(v, t);
    if (t < NSB) boff[t] = incl - v;
}
__global__ __launch_bounds__(256) void scan3g(int* __restrict__ out,
                                              const int* __restrict__ boff) {
    int i = blockIdx.x * 256 + threadIdx.x;
    if (i < LHM) out[i] += boff[blockIdx.x];
}

// ---------------- Phase C: partition edges into bucket-major order --------------
__global__ __launch_bounds__(256) void phaseC_kernel(const int* __restrict__ src,
                                                     const int* __restrict__ dst,
                                                     const int* __restrict__ base,
                                                     uint32* __restrict__ edgeTmp) {
    __shared__ int cur[NBKT];
    int t = threadIdx.x, blk = blockIdx.x;
    if (t < NBKT) cur[t] = base[t * NB + blk];
    __syncthreads();
    int e0 = blk * CHUNK;
    for (int i = t; i < CHUNK; i += 256) {
        int e = e0 + i;
        if (e < N_EDGES) {
            uint32 s = (uint32)src[e], d = (uint32)dst[e];
            int p = atomicAdd(&cur[d >> 8], 1);      // LDS atomic
            edgeTmp[p] = (s << 16) | d;              // both < 65536
        }
    }
}

// ---------------- Phase D: per-bucket counting sort + rowstart + dis ------------
__global__ __launch_bounds__(256) void phaseD_kernel(const uint32* __restrict__ edgeTmp,
                                                     const int* __restrict__ base,
                                                     int* __restrict__ rowstart,
                                                     float* __restrict__ dis,
                                                     ushort* __restrict__ e16) {
    __shared__ int cnt[256];
    __shared__ int cur[256];
    int t = threadIdx.x, b = blockIdx.x;
    int beg = base[b * NB];
    int end = (b == NBKT - 1) ? N_EDGES : base[(b + 1) * NB];
    cnt[t] = 0;
    __syncthreads();
    for (int p = beg + t; p < end; p += 256)
        atomicAdd(&cnt[edgeTmp[p] & 255], 1);
    __syncthreads();
    int c = cnt[t];
    int incl = block_incl_scan(c, t);
    int excl = incl - c;
    int node = b * 256 + t;
    if (node <= N_NODES) rowstart[node] = beg + excl;
    if (node < N_NODES) dis[node] = rsqrtf((float)(c + 1));
    cur[t] = excl;
    __syncthreads();
    for (int p = beg + t; p < end; p += 256) {
        uint32 u = edgeTmp[p];
        int r = atomicAdd(&cur[u & 255], 1);            // LDS atomic
        e16[beg + r] = (ushort)(u >> 16);
    }
}

// ---------------- W^T bf16 prep: Wt[n][k] from W[k][n] ----------------
__global__ __launch_bounds__(256) void wprep_kernel(const float* __restrict__ W1,
                                                    const float* __restrict__ W2,
                                                    ushort* __restrict__ W1t,
                                                    ushort* __restrict__ W2t) {
    const float* W = blockIdx.x ? W2 : W1;
    ushort* Wt = blockIdx.x ? W2t : W1t;
    int t = threadIdx.x;
    #pragma unroll
    for (int it = 0; it < 16; it++) {
        int fid = t + it * 256;
        int k = fid >> 5;
        int n0 = (fid & 31) * 4;
        float4 w = ((const float4*)W)[fid];
        Wt[(n0 + 0) * D + k] = f2bf(w.x);
        Wt[(n0 + 1) * D + k] = f2bf(w.y);
        Wt[(n0 + 2) * D + k] = f2bf(w.z);
        Wt[(n0 + 3) * D + k] = f2bf(w.w);
    }
}

// ---------------- Hb = bf16(dis[r] * (X @ W)) via MFMA 16x16x32 bf16 ------------
// BF16IN: X is bf16[N][D]; else fp32[N][D] (converted in regs).
template<bool BF16IN>
__global__ __launch_bounds__(256) void gemm_mfma(const void* __restrict__ Xv,
                                                 const ushort* __restrict__ Wt,
                                                 const float* __restrict__ dis,
                                                 ushort* __restrict__ Hb) {
    __shared__ ushort Cs[128 * 136];
    int t = threadIdx.x;
    int wv = t >> 6, lane = t & 63;
    int q = lane >> 4, m = lane & 15;
    int rbase = blockIdx.x * 128 + wv * 32;
    f4v zero = {0.f, 0.f, 0.f, 0.f};
    f4v acc[2][8];
    #pragma unroll
    for (int mt = 0; mt < 2; mt++)
        #pragma unroll
        for (int n = 0; n < 8; n++) acc[mt][n] = zero;

    #pragma unroll
    for (int kt = 0; kt < 4; kt++) {
        int k0 = kt * 32 + q * 8;
        s8v a[2];
        #pragma unroll
        for (int mt = 0; mt < 2; mt++) {
            int row = rbase + mt * 16 + m;
            if (row >= N_NODES) row = N_NODES - 1;
            if (BF16IN) {
                const ushort* xp = (const ushort*)Xv + (size_t)row * D + k0;
                a[mt] = *(const s8v*)xp;                       // 16B load
            } else {
                const float* xp = (const float*)Xv + (size_t)row * D + k0;
                float4 u0 = *(const float4*)xp;
                float4 u1 = *(const float4*)(xp + 4);
                s8v av;
                av[0] = (short)f2bf(u0.x); av[1] = (short)f2bf(u0.y);
                av[2] = (short)f2bf(u0.z); av[3] = (short)f2bf(u0.w);
                av[4] = (short)f2bf(u1.x); av[5] = (short)f2bf(u1.y);
                av[6] = (short)f2bf(u1.z); av[7] = (short)f2bf(u1.w);
                a[mt] = av;
            }
        }
        #pragma unroll
        for (int n = 0; n < 8; n++) {
            s8v b = *(const s8v*)(Wt + (size_t)(n * 16 + m) * D + k0);
            acc[0][n] = __builtin_amdgcn_mfma_f32_16x16x32_bf16(a[0], b, acc[0][n], 0, 0, 0);
            acc[1][n] = __builtin_amdgcn_mfma_f32_16x16x32_bf16(a[1], b, acc[1][n], 0, 0, 0);
        }
    }
    float disv[2][4];
    #pragma unroll
    for (int mt = 0; mt < 2; mt++)
        #pragma unroll
        for (int r = 0; r < 4; r++) {
            int row = rbase + mt * 16 + q * 4 + r;
            if (row >= N_NODES) row = N_NODES - 1;
            disv[mt][r] = dis[row];
        }
    #pragma unroll
    for (int mt = 0; mt < 2; mt++)
        #pragma unroll
        for (int n = 0; n < 8; n++)
            #pragma unroll
            for (int r = 0; r < 4; r++) {
                int row = wv * 32 + mt * 16 + q * 4 + r;
                Cs[row * 136 + n * 16 + m] = f2bf(acc[mt][n][r] * disv[mt][r]);
            }
    __syncthreads();
    int gbase = blockIdx.x * 128;
    #pragma unroll
    for (int it = 0; it < 8; it++) {
        int cid = t + it * 256;
        int row = cid >> 4, off = (cid & 15) * 8;
        int grow = gbase + row;
        if (grow < N_NODES) {
            s8v v = *(const s8v*)(Cs + row * 136 + off);
            *(s8v*)(Hb + (size_t)grow * D + off) = v;
        }
    }
}

// ---------------- aggregate: out = relu(dis[n]*(Hb[n]+sum Hb[src])+b) ------------
// 16 lanes per node (8 channels each, uint4 of 8 bf16), 4 nodes per wave.
// One wave-level gather = 4 rows (1KB). BF16OUT: Hout bf16, else fp32.
__device__ __forceinline__ void acc8(float* a, uint4 v) {
    a[0] += bf_lo(v.x); a[1] += bf_hi(v.x);
    a[2] += bf_lo(v.y); a[3] += bf_hi(v.y);
    a[4] += bf_lo(v.z); a[5] += bf_hi(v.z);
    a[6] += bf_lo(v.w); a[7] += bf_hi(v.w);
}

template<bool BF16OUT>
__global__ __launch_bounds__(256) void aggr_kernel(const uint4* __restrict__ Hb4,
                                                   const float* __restrict__ dis,
                                                   const int* __restrict__ rowstart,
                                                   const ushort* __restrict__ e16,
                                                   const float* __restrict__ bias,
                                                   void* __restrict__ Hout) {
    int t = threadIdx.x;
    int li = t & 15;                       // lane in group: channels li*8..li*8+7
    int n = blockIdx.x * 16 + (t >> 4);    // 50000 = 3125*16, no remainder
    float dn = dis[n];
    float a[8];
    {
        uint4 sv = Hb4[(size_t)n * 16 + li];   // self term (dis[n] folded into Hb)
        a[0] = bf_lo(sv.x); a[1] = bf_hi(sv.x);
        a[2] = bf_lo(sv.y); a[3] = bf_hi(sv.y);
        a[4] = bf_lo(sv.z); a[5] = bf_hi(sv.z);
        a[6] = bf_lo(sv.w); a[7] = bf_hi(sv.w);
    }
    int beg = rowstart[n], end = rowstart[n + 1];
    int p = beg;
    for (; p + 3 < end; p += 4) {          // 4 independent 16B gathers per lane
        int s0 = e16[p + 0], s1 = e16[p + 1], s2 = e16[p + 2], s3 = e16[p + 3];
        uint4 v0 = Hb4[(size_t)s0 * 16 + li];
        uint4 v1 = Hb4[(size_t)s1 * 16 + li];
        uint4 v2 = Hb4[(size_t)s2 * 16 + li];
        uint4 v3 = Hb4[(size_t)s3 * 16 + li];
        acc8(a, v0); acc8(a, v1); acc8(a, v2); acc8(a, v3);
    }
    for (; p < end; p++) {
        uint4 v0 = Hb4[(size_t)e16[p] * 16 + li];
        acc8(a, v0);
    }
    const float4* b4 = (const float4*)bias;
    float4 bb0 = b4[li * 2], bb1 = b4[li * 2 + 1];
    float r0 = fmaxf(fmaf(dn, a[0], bb0.x), 0.f);
    float r1 = fmaxf(fmaf(dn, a[1], bb0.y), 0.f);
    float r2 = fmaxf(fmaf(dn, a[2], bb0.z), 0.f);
    float r3 = fmaxf(fmaf(dn, a[3], bb0.w), 0.f);
    float r4 = fmaxf(fmaf(dn, a[4], bb1.x), 0.f);
    float r5 = fmaxf(fmaf(dn, a[5], bb1.y), 0.f);
    float r6 = fmaxf(fmaf(dn, a[6], bb1.z), 0.f);
    float r7 = fmaxf(fmaf(dn, a[7], bb1.w), 0.f);
    if (BF16OUT) {
        uint4 o;
        o.x = (uint32)f2bf(r0) | ((uint32)f2bf(r1) << 16);
        o.y = (uint32)f2bf(r2) | ((uint32)f2bf(r3) << 16);
        o.z = (uint32)f2bf(r4) | ((uint32)f2bf(r5) << 16);
        o.w = (uint32)f2bf(r6) | ((uint32)f2bf(r7) << 16);
        ((uint4*)Hout)[(size_t)n * 16 + li] = o;
    } else {
        float4* H4 = (float4*)Hout;
        float4 o0; o0.x = r0; o0.y = r1; o0.z = r2; o0.w = r3;
        float4 o1; o1.x = r4; o1.y = r5; o1.z = r6; o1.w = r7;
        H4[(size_t)n * 32 + li * 2]     = o0;
        H4[(size_t)n * 32 + li * 2 + 1] = o1;
    }
}

extern "C" void kernel_launch(void* const* d_in, const int* in_sizes, int n_in,
                              void* d_out, int out_size, void* d_ws, size_t ws_size,
                              hipStream_t stream) {
    const float* x  = (const float*)d_in[0];
    const int*   ei = (const int*)d_in[1];   // int32 per harness contract
    const float* W1 = (const float*)d_in[2];
    const float* b1 = (const float*)d_in[3];
    const float* W2 = (const float*)d_in[4];
    const float* b2 = (const float*)d_in[5];
    float* out = (float*)d_out;

    char* ws = (char*)d_ws;
    size_t off = 0;
    auto alloc = [&](size_t bytes) -> void* {
        void* p = ws + off;
        off += (bytes + 255) & ~(size_t)255;
        return p;
    };
    int*    histM    = (int*)alloc((size_t)LHM * 4);
    int*    base     = (int*)alloc((size_t)LHM * 4);
    int*    bsum     = (int*)alloc(256 * 4);
    int*    boff     = (int*)alloc(256 * 4);
    int*    rowstart = (int*)alloc((size_t)(N_NODES + 1) * 4);
    float*  dis      = (float*)alloc((size_t)N_NODES * 4);
    uint32* edgeTmp  = (uint32*)alloc((size_t)N_EDGES * 4);
    ushort* e16      = (ushort*)alloc((size_t)N_EDGES * 2);
    ushort* Hb       = (ushort*)alloc((size_t)N_NODES * D * 2);
    ushort* HO1      = (ushort*)alloc((size_t)N_NODES * D * 2);   // layer-1 out bf16
    ushort* W1t      = (ushort*)alloc((size_t)D * D * 2);
    ushort* W2t      = (ushort*)alloc((size_t)D * D * 2);

    const int* src = ei;             // edge_index[0]
    const int* dst = ei + N_EDGES;   // edge_index[1]

    wprep_kernel<<<2, 256, 0, stream>>>(W1, W2, W1t, W2t);
    phaseA_kernel<<<NB, 256, 0, stream>>>(dst, histM);
    scan1g<<<NSB, 256, 0, stream>>>(histM, base, bsum);
    scan2g<<<1, 256, 0, stream>>>(bsum, boff);
    scan3g<<<NSB, 256, 0, stream>>>(base, boff);
    phaseC_kernel<<<NB, 256, 0, stream>>>(src, dst, base, edgeTmp);
    phaseD_kernel<<<NBKT, 256, 0, stream>>>(edgeTmp, base, rowstart, dis, e16);

    gemm_mfma<false><<<(N_NODES + 127) / 128, 256, 0, stream>>>(x, W1t, dis, Hb);
    aggr_kernel<true><<<N_NODES / 16, 256, 0, stream>>>((const uint4*)Hb, dis, rowstart,
                                                        e16, b1, HO1);
    gemm_mfma<true><<<(N_NODES + 127) / 128, 256, 0, stream>>>(HO1, W2t, dis, Hb);
    aggr_kernel<false><<<N_NODES / 16, 256, 0, stream>>>((const uint4*)Hb, dis, rowstart,
                                                         e16, b2, out);
}

// Round 8
// 209.475 us; speedup vs baseline: 2.2867x; 1.0332x over previous
//
#include <hip/hip_runtime.h>

#define N_NODES 50000
#define N_EDGES 800000
#define D 128
#define NB 392            // partition chunk blocks
#define CHUNK 2048        // edges per chunk (392*2048 = 802816 >= 800000)
#define NBKT 391          // buckets = dst>>7 (128 nodes each)
#define LHM (NBKT * NB)   // hist matrix length 153272
#define NSB ((LHM + 255) / 256)   // 599

typedef unsigned int uint32;
typedef unsigned short ushort;
typedef __attribute__((ext_vector_type(8))) short s8v;   // 8 x bf16 bits
typedef __attribute__((ext_vector_type(4))) float f4v;   // MFMA accumulator

__device__ __forceinline__ ushort f2bf(float f) {   // RNE bf16
    unsigned u = __float_as_uint(f);
    u += 0x7FFFu + ((u >> 16) & 1u);
    return (ushort)(u >> 16);
}
__device__ __forceinline__ float bf_lo(uint32 u) { return __uint_as_float(u << 16); }
__device__ __forceinline__ float bf_hi(uint32 u) { return __uint_as_float(u & 0xFFFF0000u); }

// ---- block-wide inclusive scan helper (256 threads = 4 waves) ----
__device__ __forceinline__ int block_incl_scan(int v, int t) {
    int lane = t & 63, wv = t >> 6;
    int incl = v;
    #pragma unroll
    for (int off = 1; off < 64; off <<= 1) {
        int u = __shfl_up(incl, off, 64);
        if (lane >= off) incl += u;
    }
    __shared__ int wsums[4];
    if (lane == 63) wsums[wv] = incl;
    __syncthreads();
    int add = 0;
    if (wv > 0) add += wsums[0];
    if (wv > 1) add += wsums[1];
    if (wv > 2) add += wsums[2];
    return incl + add;
}

// ---- Phase A (+ fused wprep): per-chunk bucket histogram / W^T bf16 prep ----
__global__ __launch_bounds__(256) void phaseA_kernel(const int* __restrict__ dst,
                                                     int* __restrict__ histM,
                                                     const float* __restrict__ W1,
                                                     const float* __restrict__ W2,
                                                     ushort* __restrict__ W1t,
                                                     ushort* __restrict__ W2t) {
    __shared__ int cnt[NBKT];
    int t = threadIdx.x, blk = blockIdx.x;
    if (blk >= NB) {                      // 2 tail blocks: weight transpose+cvt
        const float* W = (blk - NB) ? W2 : W1;
        ushort* Wt = (blk - NB) ? W2t : W1t;
        #pragma unroll
        for (int it = 0; it < 16; it++) {
            int fid = t + it * 256;       // float4 id 0..4095
            int k = fid >> 5;
            int n0 = (fid & 31) * 4;
            float4 w = ((const float4*)W)[fid];
            Wt[(n0 + 0) * D + k] = f2bf(w.x);
            Wt[(n0 + 1) * D + k] = f2bf(w.y);
            Wt[(n0 + 2) * D + k] = f2bf(w.z);
            Wt[(n0 + 3) * D + k] = f2bf(w.w);
        }
        return;
    }
    for (int i = t; i < NBKT; i += 256) cnt[i] = 0;
    __syncthreads();
    int e0 = blk * CHUNK;
    for (int i = t; i < CHUNK; i += 256) {
        int e = e0 + i;
        if (e < N_EDGES) atomicAdd(&cnt[dst[e] >> 7], 1);
    }
    __syncthreads();
    for (int i = t; i < NBKT; i += 256)
        histM[i * NB + blk] = cnt[i];     // bucket-major, block-minor
}

// ---- scan pass 1: block-local exclusive + block sums ----
__global__ __launch_bounds__(256) void scan1g(const int* __restrict__ in,
                                              int* __restrict__ out,
                                              int* __restrict__ bsum) {
    int t = threadIdx.x, blk = blockIdx.x;
    int i = blk * 256 + t;
    int v = (i < LHM) ? in[i] : 0;
    int incl = block_incl_scan(v, t);
    if (i < LHM) out[i] = incl - v;
    if (t == 255) bsum[blk] = incl;
}

// ---- scan pass 2 (merged): each block reduces its bsum-prefix, adds to its tile ----
__global__ __launch_bounds__(256) void scan23g(int* __restrict__ out,
                                               const int* __restrict__ bsum) {
    int t = threadIdx.x, blk = blockIdx.x;
    // sum bsum[0..blk-1]
    int local = 0;
    for (int i = t; i < blk; i += 256) local += bsum[i];
    int lane = t & 63, wv = t >> 6;
    #pragma unroll
    for (int off = 32; off > 0; off >>= 1) local += __shfl_down(local, off, 64);
    __shared__ int ws[4];
    if (lane == 0) ws[wv] = local;
    __syncthreads();
    int boff = ws[0] + ws[1] + ws[2] + ws[3];
    int i = blk * 256 + t;
    if (i < LHM) out[i] += boff;
}

// ---- Phase C: partition edges into bucket-major order ----
__global__ __launch_bounds__(256) void phaseC_kernel(const int* __restrict__ src,
                                                     const int* __restrict__ dst,
                                                     const int* __restrict__ base,
                                                     uint32* __restrict__ edgeTmp) {
    __shared__ int cur[NBKT];
    int t = threadIdx.x, blk = blockIdx.x;
    for (int i = t; i < NBKT; i += 256) cur[i] = base[i * NB + blk];
    __syncthreads();
    int e0 = blk * CHUNK;
    for (int i = t; i < CHUNK; i += 256) {
        int e = e0 + i;
        if (e < N_EDGES) {
            uint32 s = (uint32)src[e], d = (uint32)dst[e];
            int p = atomicAdd(&cur[d >> 7], 1);      // LDS atomic
            edgeTmp[p] = (s << 16) | d;              // both < 65536
        }
    }
}

// ---- Phase D: per-bucket (128 nodes) counting sort + rowstart + dis ----
__global__ __launch_bounds__(256) void phaseD_kernel(const uint32* __restrict__ edgeTmp,
                                                     const int* __restrict__ base,
                                                     int* __restrict__ rowstart,
                                                     float* __restrict__ dis,
                                                     ushort* __restrict__ e16) {
    __shared__ int cnt[128];
    __shared__ int cur[128];
    int t = threadIdx.x, b = blockIdx.x;
    int beg = base[b * NB];
    int end = (b == NBKT - 1) ? N_EDGES : base[(b + 1) * NB];
    if (t < 128) cnt[t] = 0;
    __syncthreads();
    for (int p = beg + t; p < end; p += 256)
        atomicAdd(&cnt[edgeTmp[p] & 127], 1);
    __syncthreads();
    int c = (t < 128) ? cnt[t] : 0;
    int incl = block_incl_scan(c, t);
    int excl = incl - c;
    int node = b * 128 + t;
    if (t <= 128 && node <= N_NODES) {
        // t==128 handled via t<=128? block_incl_scan used t<256; write end-of-bucket
        if (t < 128) rowstart[node] = beg + excl;
    }
    if (t == 128 && node <= N_NODES) rowstart[node] = end;  // bucket boundary
    if (t < 128 && node < N_NODES) dis[node] = rsqrtf((float)(c + 1));
    if (t < 128) cur[t] = excl;
    __syncthreads();
    for (int p = beg + t; p < end; p += 256) {
        uint32 u = edgeTmp[p];
        int r = atomicAdd(&cur[u & 127], 1);            // LDS atomic
        e16[beg + r] = (ushort)(u >> 16);
    }
}

// ---- Hb = bf16(dis[r] * (X @ W)) via MFMA 16x16x32 bf16 ----
template<bool BF16IN>
__global__ __launch_bounds__(256) void gemm_mfma(const void* __restrict__ Xv,
                                                 const ushort* __restrict__ Wt,
                                                 const float* __restrict__ dis,
                                                 ushort* __restrict__ Hb) {
    __shared__ ushort Cs[128 * 136];
    int t = threadIdx.x;
    int wv = t >> 6, lane = t & 63;
    int q = lane >> 4, m = lane & 15;
    int rbase = blockIdx.x * 128 + wv * 32;
    f4v zero = {0.f, 0.f, 0.f, 0.f};
    f4v acc[2][8];
    #pragma unroll
    for (int mt = 0; mt < 2; mt++)
        #pragma unroll
        for (int n = 0; n < 8; n++) acc[mt][n] = zero;

    #pragma unroll
    for (int kt = 0; kt < 4; kt++) {
        int k0 = kt * 32 + q * 8;
        s8v a[2];
        #pragma unroll
        for (int mt = 0; mt < 2; mt++) {
            int row = rbase + mt * 16 + m;
            if (row >= N_NODES) row = N_NODES - 1;
            if (BF16IN) {
                const ushort* xp = (const ushort*)Xv + (size_t)row * D + k0;
                a[mt] = *(const s8v*)xp;                       // 16B load
            } else {
                const float* xp = (const float*)Xv + (size_t)row * D + k0;
                float4 u0 = *(const float4*)xp;
                float4 u1 = *(const float4*)(xp + 4);
                s8v av;
                av[0] = (short)f2bf(u0.x); av[1] = (short)f2bf(u0.y);
                av[2] = (short)f2bf(u0.z); av[3] = (short)f2bf(u0.w);
                av[4] = (short)f2bf(u1.x); av[5] = (short)f2bf(u1.y);
                av[6] = (short)f2bf(u1.z); av[7] = (short)f2bf(u1.w);
                a[mt] = av;
            }
        }
        #pragma unroll
        for (int n = 0; n < 8; n++) {
            s8v b = *(const s8v*)(Wt + (size_t)(n * 16 + m) * D + k0);
            acc[0][n] = __builtin_amdgcn_mfma_f32_16x16x32_bf16(a[0], b, acc[0][n], 0, 0, 0);
            acc[1][n] = __builtin_amdgcn_mfma_f32_16x16x32_bf16(a[1], b, acc[1][n], 0, 0, 0);
        }
    }
    float disv[2][4];
    #pragma unroll
    for (int mt = 0; mt < 2; mt++)
        #pragma unroll
        for (int r = 0; r < 4; r++) {
            int row = rbase + mt * 16 + q * 4 + r;
            if (row >= N_NODES) row = N_NODES - 1;
            disv[mt][r] = dis[row];
        }
    #pragma unroll
    for (int mt = 0; mt < 2; mt++)
        #pragma unroll
        for (int n = 0; n < 8; n++)
            #pragma unroll
            for (int r = 0; r < 4; r++) {
                int row = wv * 32 + mt * 16 + q * 4 + r;
                Cs[row * 136 + n * 16 + m] = f2bf(acc[mt][n][r] * disv[mt][r]);
            }
    __syncthreads();
    int gbase = blockIdx.x * 128;
    #pragma unroll
    for (int it = 0; it < 8; it++) {
        int cid = t + it * 256;
        int row = cid >> 4, off = (cid & 15) * 8;
        int grow = gbase + row;
        if (grow < N_NODES) {
            s8v v = *(const s8v*)(Cs + row * 136 + off);
            *(s8v*)(Hb + (size_t)grow * D + off) = v;
        }
    }
}

// ---- aggregate: out = relu(dis[n]*(Hb[n]+sum Hb[src])+b), 16 lanes/node ----
__device__ __forceinline__ void acc8(float* a, uint4 v) {
    a[0] += bf_lo(v.x); a[1] += bf_hi(v.x);
    a[2] += bf_lo(v.y); a[3] += bf_hi(v.y);
    a[4] += bf_lo(v.z); a[5] += bf_hi(v.z);
    a[6] += bf_lo(v.w); a[7] += bf_hi(v.w);
}

template<bool BF16OUT>
__global__ __launch_bounds__(256) void aggr_kernel(const uint4* __restrict__ Hb4,
                                                   const float* __restrict__ dis,
                                                   const int* __restrict__ rowstart,
                                                   const ushort* __restrict__ e16,
                                                   const float* __restrict__ bias,
                                                   void* __restrict__ Hout) {
    int t = threadIdx.x;
    int li = t & 15;                       // lane in group: channels li*8..li*8+7
    int n = blockIdx.x * 16 + (t >> 4);    // 50000 = 3125*16
    float dn = dis[n];
    float a[8];
    {
        uint4 sv = Hb4[(size_t)n * 16 + li];   // self term (dis[n] folded into Hb)
        a[0] = bf_lo(sv.x); a[1] = bf_hi(sv.x);
        a[2] = bf_lo(sv.y); a[3] = bf_hi(sv.y);
        a[4] = bf_lo(sv.z); a[5] = bf_hi(sv.z);
        a[6] = bf_lo(sv.w); a[7] = bf_hi(sv.w);
    }
    int beg = rowstart[n], end = rowstart[n + 1];
    int p = beg;
    for (; p + 7 < end; p += 8) {          // 8 outstanding 16B gathers per lane
        int s[8];
        #pragma unroll
        for (int j = 0; j < 8; j++) s[j] = e16[p + j];
        uint4 v[8];
        #pragma unroll
        for (int j = 0; j < 8; j++) v[j] = Hb4[(size_t)s[j] * 16 + li];
        #pragma unroll
        for (int j = 0; j < 8; j++) acc8(a, v[j]);
    }
    for (; p + 3 < end; p += 4) {
        int s0 = e16[p + 0], s1 = e16[p + 1], s2 = e16[p + 2], s3 = e16[p + 3];
        uint4 v0 = Hb4[(size_t)s0 * 16 + li];
        uint4 v1 = Hb4[(size_t)s1 * 16 + li];
        uint4 v2 = Hb4[(size_t)s2 * 16 + li];
        uint4 v3 = Hb4[(size_t)s3 * 16 + li];
        acc8(a, v0); acc8(a, v1); acc8(a, v2); acc8(a, v3);
    }
    for (; p < end; p++) {
        uint4 v0 = Hb4[(size_t)e16[p] * 16 + li];
        acc8(a, v0);
    }
    const float4* b4 = (const float4*)bias;
    float4 bb0 = b4[li * 2], bb1 = b4[li * 2 + 1];
    float r0 = fmaxf(fmaf(dn, a[0], bb0.x), 0.f);
    float r1 = fmaxf(fmaf(dn, a[1], bb0.y), 0.f);
    float r2 = fmaxf(fmaf(dn, a[2], bb0.z), 0.f);
    float r3 = fmaxf(fmaf(dn, a[3], bb0.w), 0.f);
    float r4 = fmaxf(fmaf(dn, a[4], bb1.x), 0.f);
    float r5 = fmaxf(fmaf(dn, a[5], bb1.y), 0.f);
    float r6 = fmaxf(fmaf(dn, a[6], bb1.z), 0.f);
    float r7 = fmaxf(fmaf(dn, a[7], bb1.w), 0.f);
    if (BF16OUT) {
        uint4 o;
        o.x = (uint32)f2bf(r0) | ((uint32)f2bf(r1) << 16);
        o.y = (uint32)f2bf(r2) | ((uint32)f2bf(r3) << 16);
        o.z = (uint32)f2bf(r4) | ((uint32)f2bf(r5) << 16);
        o.w = (uint32)f2bf(r6) | ((uint32)f2bf(r7) << 16);
        ((uint4*)Hout)[(size_t)n * 16 + li] = o;
    } else {
        float4* H4 = (float4*)Hout;
        float4 o0; o0.x = r0; o0.y = r1; o0.z = r2; o0.w = r3;
        float4 o1; o1.x = r4; o1.y = r5; o1.z = r6; o1.w = r7;
        H4[(size_t)n * 32 + li * 2]     = o0;
        H4[(size_t)n * 32 + li * 2 + 1] = o1;
    }
}

extern "C" void kernel_launch(void* const* d_in, const int* in_sizes, int n_in,
                              void* d_out, int out_size, void* d_ws, size_t ws_size,
                              hipStream_t stream) {
    const float* x  = (const float*)d_in[0];
    const int*   ei = (const int*)d_in[1];   // int32 per harness contract
    const float* W1 = (const float*)d_in[2];
    const float* b1 = (const float*)d_in[3];
    const float* W2 = (const float*)d_in[4];
    const float* b2 = (const float*)d_in[5];
    float* out = (float*)d_out;

    char* ws = (char*)d_ws;
    size_t off = 0;
    auto alloc = [&](size_t bytes) -> void* {
        void* p = ws + off;
        off += (bytes + 255) & ~(size_t)255;
        return p;
    };
    int*    histM    = (int*)alloc((size_t)LHM * 4);
    int*    base     = (int*)alloc((size_t)LHM * 4);
    int*    bsum     = (int*)alloc((size_t)NSB * 4);
    int*    rowstart = (int*)alloc((size_t)(N_NODES + 1) * 4);
    float*  dis      = (float*)alloc((size_t)N_NODES * 4);
    uint32* edgeTmp  = (uint32*)alloc((size_t)N_EDGES * 4);
    ushort* e16      = (ushort*)alloc((size_t)N_EDGES * 2);
    ushort* Hb       = (ushort*)alloc((size_t)N_NODES * D * 2);
    ushort* HO1      = (ushort*)alloc((size_t)N_NODES * D * 2);   // layer-1 out bf16
    ushort* W1t      = (ushort*)alloc((size_t)D * D * 2);
    ushort* W2t      = (ushort*)alloc((size_t)D * D * 2);

    const int* src = ei;             // edge_index[0]
    const int* dst = ei + N_EDGES;   // edge_index[1]

    phaseA_kernel<<<NB + 2, 256, 0, stream>>>(dst, histM, W1, W2, W1t, W2t);
    scan1g<<<NSB, 256, 0, stream>>>(histM, base, bsum);
    scan23g<<<NSB, 256, 0, stream>>>(base, bsum);
    phaseC_kernel<<<NB, 256, 0, stream>>>(src, dst, base, edgeTmp);
    phaseD_kernel<<<NBKT, 256, 0, stream>>>(edgeTmp, base, rowstart, dis, e16);

    gemm_mfma<false><<<(N_NODES + 127) / 128, 256, 0, stream>>>(x, W1t, dis, Hb);
    aggr_kernel<true><<<N_NODES / 16, 256, 0, stream>>>((const uint4*)Hb, dis, rowstart,
                                                        e16, b1, HO1);
    gemm_mfma<true><<<(N_NODES + 127) / 128, 256, 0, stream>>>(HO1, W2t, dis, Hb);
    aggr_kernel<false><<<N_NODES / 16, 256, 0, stream>>>((const uint4*)Hb, dis, rowstart,
                                                         e16, b2, out);
}